// Round 1
// baseline (79.068 us; speedup 1.0000x reference)
//
#include <hip/hip_runtime.h>

// LengthRegulator: B=32, L=1024, D=512, T=max_len=4096
// out[b,t,:] = x[b, idx(b,t), :] where idx = searchsorted(cumsum(dur[b]), t, 'right'),
// zeroed for t >= total duration of row b.

#define B_ 32
#define L_ 1024
#define D_ 512
#define T_ 4096

// Kernel 1: per-row inclusive scan of durations + scatter frame->token map.
// One block per row, L_ threads.
__global__ __launch_bounds__(L_) void lr_scan_scatter(const int* __restrict__ dur,
                                                      int* __restrict__ idxmap) {
    __shared__ int s[L_];
    const int b = blockIdx.x;
    const int i = threadIdx.x;

    int d = dur[b * L_ + i];
    if (d < 0) d = 0;
    s[i] = d;
    __syncthreads();

    // Hillis-Steele inclusive scan over L_=1024 elements.
    #pragma unroll
    for (int off = 1; off < L_; off <<= 1) {
        int v = (i >= off) ? s[i - off] : 0;
        __syncthreads();
        s[i] += v;
        __syncthreads();
    }

    const int incl = s[i];
    const int excl = incl - d;
    const int total = s[L_ - 1];

    // Scatter: frames [excl, min(incl, T_)) belong to token i.
    int hi = incl < T_ ? incl : T_;
    for (int t = excl; t < hi; ++t) {
        idxmap[b * T_ + t] = i;
    }
    // Frames [total, T_) are padding -> -1.
    for (int t = (total < T_ ? total : T_) + i; t < T_; t += L_) {
        idxmap[b * T_ + t] = -1;
    }
}

// Kernel 2: gather. One block per (b, t) output frame; 128 threads x float4 = 512 floats.
__global__ __launch_bounds__(128) void lr_gather(const float* __restrict__ x,
                                                 const int* __restrict__ idxmap,
                                                 float* __restrict__ out) {
    const int bt = blockIdx.x;           // b * T_ + t
    const int b = bt >> 12;              // T_ = 4096
    const int id = idxmap[bt];
    const int d4 = threadIdx.x;          // 0..127 float4 slots

    float4* o = reinterpret_cast<float4*>(out + (size_t)bt * D_);
    if (id >= 0) {
        const float4* src = reinterpret_cast<const float4*>(
            x + ((size_t)b * L_ + (size_t)id) * D_);
        o[d4] = src[d4];
    } else {
        o[d4] = make_float4(0.f, 0.f, 0.f, 0.f);
    }
}

extern "C" void kernel_launch(void* const* d_in, const int* in_sizes, int n_in,
                              void* d_out, int out_size, void* d_ws, size_t ws_size,
                              hipStream_t stream) {
    const float* x = (const float*)d_in[0];
    const int* dur = (const int*)d_in[1];
    // d_in[2] is max_len (== 4096), compile-time constant here.
    float* out = (float*)d_out;
    int* idxmap = (int*)d_ws;            // B_*T_ ints = 512 KiB

    lr_scan_scatter<<<B_, L_, 0, stream>>>(dur, idxmap);
    lr_gather<<<B_ * T_, 128, 0, stream>>>(x, idxmap, out);
}

// Round 2
// 74.452 us; speedup vs baseline: 1.0620x; 1.0620x over previous
//
#include <hip/hip_runtime.h>

// LengthRegulator: B=32, L=1024, D=512, T=max_len=4096
// out[b,t,:] = x[b, idx(b,t), :] where idx = searchsorted(cumsum(dur[b]), t, 'right'),
// zeroed for t >= total duration of row b.

#define B_ 32
#define L_ 1024
#define D_ 512
#define T_ 4096

// Kernel 1: per-row inclusive scan of durations + scatter frame->token map.
// One block per row, L_ threads. Wave-level shfl scan, 2 barriers total.
__global__ __launch_bounds__(L_) void lr_scan_scatter(const int* __restrict__ dur,
                                                      int* __restrict__ idxmap) {
    __shared__ int wsum[16];             // 16 waves of 64
    const int b = blockIdx.x;
    const int i = threadIdx.x;
    const int lane = i & 63;
    const int wave = i >> 6;

    int d = dur[b * L_ + i];
    if (d < 0) d = 0;

    // Inclusive scan within the 64-lane wave (no barriers).
    int v = d;
    #pragma unroll
    for (int off = 1; off < 64; off <<= 1) {
        int n = __shfl_up(v, off, 64);
        if (lane >= off) v += n;
    }
    if (lane == 63) wsum[wave] = v;
    __syncthreads();

    // Wave 0 scans the 16 per-wave totals.
    if (wave == 0 && lane < 16) {
        int w = wsum[lane];
        #pragma unroll
        for (int off = 1; off < 16; off <<= 1) {
            int n = __shfl_up(w, off, 64);
            if (lane >= off) w += n;
        }
        wsum[lane] = w;                  // inclusive totals
    }
    __syncthreads();

    const int waveoff = (wave == 0) ? 0 : wsum[wave - 1];
    const int incl = v + waveoff;
    const int excl = incl - d;
    const int total = wsum[15];

    // Scatter: frames [excl, min(incl, T_)) belong to token i (d <= 7 writes).
    int hi = incl < T_ ? incl : T_;
    for (int t = excl; t < hi; ++t) {
        idxmap[b * T_ + t] = i;
    }
    // Frames [total, T_) are padding -> -1.
    for (int t = (total < T_ ? total : T_) + i; t < T_; t += L_) {
        idxmap[b * T_ + t] = -1;
    }
}

// Kernel 2: gather, grid-stride over float4 slots.
// 2048 blocks x 256 threads; each thread does 32 iterations of 16B load+store.
__global__ __launch_bounds__(256) void lr_gather(const float* __restrict__ x,
                                                 const int* __restrict__ idxmap,
                                                 float* __restrict__ out) {
    const int total4 = B_ * T_ * (D_ / 4);     // 16,777,216 float4 slots
    const int stride = gridDim.x * 256;
    float4* o = reinterpret_cast<float4*>(out);

    for (int g = blockIdx.x * 256 + threadIdx.x; g < total4; g += stride) {
        const int bt = g >> 7;                 // D_/4 = 128 slots per frame
        const int slot = g & 127;
        const int b = bt >> 12;                // T_ = 4096
        const int id = idxmap[bt];
        float4 v = make_float4(0.f, 0.f, 0.f, 0.f);
        if (id >= 0) {
            v = reinterpret_cast<const float4*>(
                    x + ((size_t)((b << 10) + id)) * D_)[slot];
        }
        o[g] = v;
    }
}

extern "C" void kernel_launch(void* const* d_in, const int* in_sizes, int n_in,
                              void* d_out, int out_size, void* d_ws, size_t ws_size,
                              hipStream_t stream) {
    const float* x = (const float*)d_in[0];
    const int* dur = (const int*)d_in[1];
    // d_in[2] is max_len (== 4096), compile-time constant here.
    float* out = (float*)d_out;
    int* idxmap = (int*)d_ws;                  // B_*T_ ints = 512 KiB scratch

    lr_scan_scatter<<<B_, L_, 0, stream>>>(dur, idxmap);
    lr_gather<<<2048, 256, 0, stream>>>(x, idxmap, out);
}